// Round 8
// baseline (789.773 us; speedup 1.0000x reference)
//
#include <hip/hip_runtime.h>

#define NF 64
#define NH 32
#define NK 16
#define NNODES 15
#define BLOCK 512
#define NWAVES (BLOCK / 64)

// r8 = r5 (best measured: 373us, VGPR 60, LDS 36KB) with the ONLY change
// being the occupancy attribute: waves_per_eu(2,4) -> (8,8).
//   * r5's 41% occupancy was the attribute's 4-waves/EU cap, not a HW limit:
//     VGPR 60 and 4x36KB=145KB<=160KB LDS permit 8 waves/EU (32 waves/CU).
//   * r6 (barrier-free) + r7 (VMEM W2, occupancy 22%) proved the stall is
//     memory latency vs resident waves; doubling TLP attacks exactly that.
//   * (8,8) also pins the allocator to <=64 VGPR; r5's body needed 60.
//     Spill guard: WRITE_SIZE must stay ~2.5 MB.
// Delivery design unchanged from r5 (measured best of three alternatives):
//   W2 staged per-level in LDS (broadcast ds_read_b128, 2-way on boundary
//   waves is free per m136); W1 per-lane float4 VMEM; h2 fused into logits
//   (no runtime-indexed register arrays; rolled g indexes memory only).

__global__ __attribute__((amdgpu_flat_work_group_size(BLOCK, BLOCK),
                          amdgpu_waves_per_eu(8, 8)))
void tree_mlp_kernel(
    const float* __restrict__ x,
    const float* __restrict__ W1, const float* __restrict__ b1,
    const float* __restrict__ W2, const float* __restrict__ b2,
    const float* __restrict__ W3, const float* __restrict__ b3,
    const float* __restrict__ leaf_best, const int* __restrict__ subset_idx,
    float* __restrict__ out, int N)
{
    __shared__ __align__(16) float W2Lv[8 * 1024];   // 32 KB: this level's nodes
    __shared__ int      subL[NNODES * NK];           // 960 B
    __shared__ unsigned permL[BLOCK];                // 2048 B
    __shared__ int      sortL[64];                   // nb*NWAVES <= 64

    const int tid  = threadIdx.x;
    const int lane = tid & 63;
    const int wv   = tid >> 6;

    // Level-0 staging fused with subL load under the single initial barrier.
    for (int i = tid; i < NNODES * NK; i += BLOCK) subL[i] = subset_idx[i];
    {
        const float4* src = (const float4*)W2;       // node 0
        float4* dst = (float4*)W2Lv;
        for (int i = tid; i < 256; i += BLOCK) dst[i] = src[i];
    }
    __syncthreads();

    const int s = blockIdx.x * BLOCK + tid;
    int valid = (s < N) ? 1 : 0;
    int id    = valid ? s : 0;      // invalid lanes shadow sample 0 (stay live for ballots)
    int loc = 0, off = 0;

    #pragma unroll 1   // keep level loop rolled (I$)
    for (int level = 0; level < 4; ++level) {
        if (level > 0) {
            // ---- in-block counting sort by loc (nb buckets), ballot-based ----
            const int nb = 1 << level;
            int myrank = 0;
            #pragma unroll 1
            for (int b = 0; b < nb; ++b) {
                const unsigned long long m = __ballot(loc == b);
                if (loc == b)
                    myrank = __popcll(m & ((1ull << lane) - 1ull));
                if (lane == 0)
                    sortL[b * NWAVES + wv] = __popcll(m);
            }
            __syncthreads();   // counts visible; prior-level W2Lv reads done

            // Stage this level's W2 slice (overlaps wave-0's scan).
            {
                const int cnt4 = (1 << level) * 256;            // float4s
                const float4* src = (const float4*)(W2 + (size_t)off * 1024);
                float4* dst = (float4*)W2Lv;
                for (int i = tid; i < cnt4; i += BLOCK) dst[i] = src[i];
            }
            // Wave-parallel exclusive scan over (bucket, wave) counts.
            if (wv == 0) {
                const int cnt = nb * NWAVES;                    // 16/32/64
                int v = (lane < cnt) ? sortL[lane] : 0;
                int incl = v;
                #pragma unroll
                for (int d = 1; d < 64; d <<= 1) {
                    int t = __shfl_up(incl, d, 64);
                    if (lane >= d) incl += t;
                }
                if (lane < cnt) sortL[lane] = incl - v;
            }
            __syncthreads();

            const int slot = sortL[loc * NWAVES + wv] + myrank;
            permL[slot] = ((unsigned)id << 5) | ((unsigned)valid << 4) | (unsigned)loc;
            __syncthreads();
            const unsigned p = permL[tid];
            id    = (int)(p >> 5);
            valid = (int)((p >> 4) & 1u);
            loc   = (int)(p & 15u);
            __syncthreads();           // protect permL/sortL reuse next level
        }

        const int node = off + loc;    // wave-uniform after sort (boundaries: 2 nodes)
        const float* xr = x + (size_t)id * NF;

        // Per-lane subset gather; dies after h1.
        float xs[NK];
        const int* si = subL + node * NK;
        #pragma unroll
        for (int k = 0; k < NK; ++k) xs[k] = xr[si[k]];

        // h1 = leaky(W1[node] @ xs + b1) : per-lane float4 VMEM (L1-hit).
        float h1v[NH];
        {
            const float4* w1g = (const float4*)(W1 + node * (NH * NK));
            const float*  b1g = b1 + node * NH;
            #pragma unroll
            for (int j = 0; j < NH; ++j) {
                float acc = b1g[j];
                #pragma unroll
                for (int q = 0; q < NK / 4; ++q) {
                    const float4 t = w1g[j * 4 + q];
                    acc += t.x * xs[q * 4 + 0];
                    acc += t.y * xs[q * 4 + 1];
                    acc += t.z * xs[q * 4 + 2];
                    acc += t.w * xs[q * 4 + 3];
                }
                h1v[j] = (acc >= 0.f) ? acc : 0.01f * acc;
            }
        }

        // h2 fused into logits. W2 row from LDS (broadcast/2-way reads);
        // runtime g indexes MEMORY only, h1v indices static (k fully unrolled).
        const float* w2l = W2Lv + (loc << 10);        // local node = loc
        const float* bb2 = b2 + node * NH;
        const float* w3g = W3 + node * 2 * NH;
        float l0 = b3[node * 2 + 0];
        float l1 = b3[node * 2 + 1];

        #pragma unroll 2
        for (int g = 0; g < NH; ++g) {
            float acc = bb2[g];
            const float4* row = (const float4*)(w2l + g * NH);
            #pragma unroll
            for (int q = 0; q < NH / 4; ++q) {
                const float4 t = row[q];
                acc += t.x * h1v[q * 4 + 0];
                acc += t.y * h1v[q * 4 + 1];
                acc += t.z * h1v[q * 4 + 2];
                acc += t.w * h1v[q * 4 + 3];
            }
            const float h2 = (acc >= 0.f) ? acc : 0.01f * acc;
            l0 += w3g[g]      * h2;
            l1 += w3g[NH + g] * h2;
        }

        const int bit = (l0 < l1) ? 1 : 0;
        loc = 2 * loc + bit;
        off = 2 * off + 1;   // node offsets: 0, 1, 3, 7
    }

    if (valid) out[id] = leaf_best[loc];
}

extern "C" void kernel_launch(void* const* d_in, const int* in_sizes, int n_in,
                              void* d_out, int out_size, void* d_ws, size_t ws_size,
                              hipStream_t stream) {
    const float* x         = (const float*)d_in[0];
    const float* W1        = (const float*)d_in[1];
    const float* b1        = (const float*)d_in[2];
    const float* W2        = (const float*)d_in[3];
    const float* b2        = (const float*)d_in[4];
    const float* W3        = (const float*)d_in[5];
    const float* b3        = (const float*)d_in[6];
    const float* leaf_best = (const float*)d_in[7];
    const int*   subset    = (const int*)d_in[8];

    const int N = in_sizes[0] / NF;
    const int grid = (N + BLOCK - 1) / BLOCK;
    tree_mlp_kernel<<<grid, BLOCK, 0, stream>>>(
        x, W1, b1, W2, b2, W3, b3, leaf_best, subset, (float*)d_out, N);
}

// Round 9
// 488.275 us; speedup vs baseline: 1.6175x; 1.6175x over previous
//
#include <hip/hip_runtime.h>

#define NF 64
#define NH 32
#define NK 16
#define NNODES 15
#define BLOCK 512
#define NWAVES (BLOCK / 64)

// r9 = r5 (best measured: 373us, VGPR 60, LDS 36KB) with the occupancy
// attribute changed to waves_per_eu(4, 8).
//   Evidence (r5 vs r8 A/B):
//   * r5 (2,4): VGPR 60, no spill, occupancy 41% (capped by max=4) -> 373us
//   * r8 (8,8): occupancy 73% (cap lifted) BUT allocator pinned VGPR to 32
//     -> 750 MB scratch spill -> 676us
//   (4,8) decouples the two: min=4 budgets 128 VGPR (body needs ~60, no
//   spill), max=8 lets residency hit the LDS limit (4 blocks/CU = 8 w/EU).
// Delivery design unchanged from r5 (measured best of LDS/SMEM/VMEM):
//   W2 staged per-level in LDS (broadcast ds_read_b128, 2-way boundary free
//   per m136); W1 per-lane float4 VMEM; h2 fused into logits (no
//   runtime-indexed register arrays; rolled g indexes memory only).

__global__ __attribute__((amdgpu_flat_work_group_size(BLOCK, BLOCK),
                          amdgpu_waves_per_eu(4, 8)))
void tree_mlp_kernel(
    const float* __restrict__ x,
    const float* __restrict__ W1, const float* __restrict__ b1,
    const float* __restrict__ W2, const float* __restrict__ b2,
    const float* __restrict__ W3, const float* __restrict__ b3,
    const float* __restrict__ leaf_best, const int* __restrict__ subset_idx,
    float* __restrict__ out, int N)
{
    __shared__ __align__(16) float W2Lv[8 * 1024];   // 32 KB: this level's nodes
    __shared__ int      subL[NNODES * NK];           // 960 B
    __shared__ unsigned permL[BLOCK];                // 2048 B
    __shared__ int      sortL[64];                   // nb*NWAVES <= 64

    const int tid  = threadIdx.x;
    const int lane = tid & 63;
    const int wv   = tid >> 6;

    // Level-0 staging fused with subL load under the single initial barrier.
    for (int i = tid; i < NNODES * NK; i += BLOCK) subL[i] = subset_idx[i];
    {
        const float4* src = (const float4*)W2;       // node 0
        float4* dst = (float4*)W2Lv;
        for (int i = tid; i < 256; i += BLOCK) dst[i] = src[i];
    }
    __syncthreads();

    const int s = blockIdx.x * BLOCK + tid;
    int valid = (s < N) ? 1 : 0;
    int id    = valid ? s : 0;      // invalid lanes shadow sample 0 (stay live for ballots)
    int loc = 0, off = 0;

    #pragma unroll 1   // keep level loop rolled (I$)
    for (int level = 0; level < 4; ++level) {
        if (level > 0) {
            // ---- in-block counting sort by loc (nb buckets), ballot-based ----
            const int nb = 1 << level;
            int myrank = 0;
            #pragma unroll 1
            for (int b = 0; b < nb; ++b) {
                const unsigned long long m = __ballot(loc == b);
                if (loc == b)
                    myrank = __popcll(m & ((1ull << lane) - 1ull));
                if (lane == 0)
                    sortL[b * NWAVES + wv] = __popcll(m);
            }
            __syncthreads();   // counts visible; prior-level W2Lv reads done

            // Stage this level's W2 slice (overlaps wave-0's scan).
            {
                const int cnt4 = (1 << level) * 256;            // float4s
                const float4* src = (const float4*)(W2 + (size_t)off * 1024);
                float4* dst = (float4*)W2Lv;
                for (int i = tid; i < cnt4; i += BLOCK) dst[i] = src[i];
            }
            // Wave-parallel exclusive scan over (bucket, wave) counts.
            if (wv == 0) {
                const int cnt = nb * NWAVES;                    // 16/32/64
                int v = (lane < cnt) ? sortL[lane] : 0;
                int incl = v;
                #pragma unroll
                for (int d = 1; d < 64; d <<= 1) {
                    int t = __shfl_up(incl, d, 64);
                    if (lane >= d) incl += t;
                }
                if (lane < cnt) sortL[lane] = incl - v;
            }
            __syncthreads();

            const int slot = sortL[loc * NWAVES + wv] + myrank;
            permL[slot] = ((unsigned)id << 5) | ((unsigned)valid << 4) | (unsigned)loc;
            __syncthreads();
            const unsigned p = permL[tid];
            id    = (int)(p >> 5);
            valid = (int)((p >> 4) & 1u);
            loc   = (int)(p & 15u);
            __syncthreads();           // protect permL/sortL reuse next level
        }

        const int node = off + loc;    // wave-uniform after sort (boundaries: 2 nodes)
        const float* xr = x + (size_t)id * NF;

        // Per-lane subset gather; dies after h1.
        float xs[NK];
        const int* si = subL + node * NK;
        #pragma unroll
        for (int k = 0; k < NK; ++k) xs[k] = xr[si[k]];

        // h1 = leaky(W1[node] @ xs + b1) : per-lane float4 VMEM (L1-hit).
        float h1v[NH];
        {
            const float4* w1g = (const float4*)(W1 + node * (NH * NK));
            const float*  b1g = b1 + node * NH;
            #pragma unroll
            for (int j = 0; j < NH; ++j) {
                float acc = b1g[j];
                #pragma unroll
                for (int q = 0; q < NK / 4; ++q) {
                    const float4 t = w1g[j * 4 + q];
                    acc += t.x * xs[q * 4 + 0];
                    acc += t.y * xs[q * 4 + 1];
                    acc += t.z * xs[q * 4 + 2];
                    acc += t.w * xs[q * 4 + 3];
                }
                h1v[j] = (acc >= 0.f) ? acc : 0.01f * acc;
            }
        }

        // h2 fused into logits. W2 row from LDS (broadcast/2-way reads);
        // runtime g indexes MEMORY only, h1v indices static (k fully unrolled).
        const float* w2l = W2Lv + (loc << 10);        // local node = loc
        const float* bb2 = b2 + node * NH;
        const float* w3g = W3 + node * 2 * NH;
        float l0 = b3[node * 2 + 0];
        float l1 = b3[node * 2 + 1];

        #pragma unroll 2
        for (int g = 0; g < NH; ++g) {
            float acc = bb2[g];
            const float4* row = (const float4*)(w2l + g * NH);
            #pragma unroll
            for (int q = 0; q < NH / 4; ++q) {
                const float4 t = row[q];
                acc += t.x * h1v[q * 4 + 0];
                acc += t.y * h1v[q * 4 + 1];
                acc += t.z * h1v[q * 4 + 2];
                acc += t.w * h1v[q * 4 + 3];
            }
            const float h2 = (acc >= 0.f) ? acc : 0.01f * acc;
            l0 += w3g[g]      * h2;
            l1 += w3g[NH + g] * h2;
        }

        const int bit = (l0 < l1) ? 1 : 0;
        loc = 2 * loc + bit;
        off = 2 * off + 1;   // node offsets: 0, 1, 3, 7
    }

    if (valid) out[id] = leaf_best[loc];
}

extern "C" void kernel_launch(void* const* d_in, const int* in_sizes, int n_in,
                              void* d_out, int out_size, void* d_ws, size_t ws_size,
                              hipStream_t stream) {
    const float* x         = (const float*)d_in[0];
    const float* W1        = (const float*)d_in[1];
    const float* b1        = (const float*)d_in[2];
    const float* W2        = (const float*)d_in[3];
    const float* b2        = (const float*)d_in[4];
    const float* W3        = (const float*)d_in[5];
    const float* b3        = (const float*)d_in[6];
    const float* leaf_best = (const float*)d_in[7];
    const int*   subset    = (const int*)d_in[8];

    const int N = in_sizes[0] / NF;
    const int grid = (N + BLOCK - 1) / BLOCK;
    tree_mlp_kernel<<<grid, BLOCK, 0, stream>>>(
        x, W1, b1, W2, b2, W3, b3, leaf_best, subset, (float*)d_out, N);
}

// Round 10
// 434.331 us; speedup vs baseline: 1.8184x; 1.1242x over previous
//
#include <hip/hip_runtime.h>

#define NF 64
#define NH 32
#define NK 16
#define NNODES 15
#define BLOCK 512
#define NWAVES (BLOCK / 64)
#define SPB (2 * BLOCK)          // samples per block (2 per lane)

// r10: TWO samples per lane. Pipe model from r9's counters: LDS pipe (1/CU)
// carries ~200us of W2-broadcast + staging traffic (54% of runtime) while
// VALU needs only ~46us/SIMD -> LDS is the structural wall, and its traffic
// scales with WAVES, not samples. Pairing 2 samples/lane:
//   * shared-node pairs (consecutive sorted slots; ~65% of wave-levels,
//     wave-uniform __all branch) read each weight ONCE for 2 FMA chains
//     -> LDS reads/sample halve; dual-path fallback == r5 body twice.
//   * blocks halve -> W2 staging writes halve; sort cost/sample halves.
//   * 2 independent FMA chains/lane hide v_fmac dep latency (ILP 2x).
// Register rules (r1-r3): no runtime-indexed reg arrays; no fully-unrolled
// scalar-weight blocks; rolled g indexes memory only. FP accumulation order
// per sample identical to r5 (absmax must stay 0).
// Occupancy lesson (r8/r9): attribute min sets allocator budget only;
// (2,4) gives a 256-VGPR budget, body needs ~110 -> no spill.
// Spill guard: WRITE_SIZE must stay ~2.5 MB.

__global__ __attribute__((amdgpu_flat_work_group_size(BLOCK, BLOCK),
                          amdgpu_waves_per_eu(2, 4)))
void tree_mlp_kernel(
    const float* __restrict__ x,
    const float* __restrict__ W1, const float* __restrict__ b1,
    const float* __restrict__ W2, const float* __restrict__ b2,
    const float* __restrict__ W3, const float* __restrict__ b3,
    const float* __restrict__ leaf_best, const int* __restrict__ subset_idx,
    float* __restrict__ out, int N)
{
    __shared__ __align__(16) float W2Lv[8 * 1024];   // 32 KB: this level's nodes
    __shared__ int      subL[NNODES * NK];           // 960 B
    __shared__ unsigned permL[SPB];                  // 4096 B
    __shared__ int      sortL[64];                   // nb*NWAVES <= 64

    const int tid  = threadIdx.x;
    const int lane = tid & 63;
    const int wv   = tid >> 6;
    const unsigned long long lt =
        (lane == 0) ? 0ull : ((~0ull) >> (64 - lane));

    for (int i = tid; i < NNODES * NK; i += BLOCK) subL[i] = subset_idx[i];
    {
        const float4* src = (const float4*)W2;       // node 0
        float4* dst = (float4*)W2Lv;
        for (int i = tid; i < 256; i += BLOCK) dst[i] = src[i];
    }
    __syncthreads();

    const int base = blockIdx.x * SPB;
    int idA = base + tid;
    int idB = base + BLOCK + tid;
    int vA = (idA < N) ? 1 : 0; if (!vA) idA = 0;
    int vB = (idB < N) ? 1 : 0; if (!vB) idB = 0;
    int locA = 0, locB = 0, off = 0;

    #pragma unroll 1   // keep level loop rolled (I$)
    for (int level = 0; level < 4; ++level) {
        if (level > 0) {
            // ---- counting sort of 1024 items by loc, ballot-based ----
            const int nb = 1 << level;
            int rkA = 0, rkB = 0;
            #pragma unroll 1
            for (int b = 0; b < nb; ++b) {
                const unsigned long long mA = __ballot(locA == b);
                const unsigned long long mB = __ballot(locB == b);
                if (locA == b) rkA = __popcll(mA & lt);
                if (locB == b) rkB = __popcll(mA) + __popcll(mB & lt);
                if (lane == 0)
                    sortL[b * NWAVES + wv] = __popcll(mA) + __popcll(mB);
            }
            __syncthreads();   // counts visible; prior-level W2Lv reads done

            // Stage this level's W2 slice (overlaps wave-0's scan).
            {
                const int cnt4 = (1 << level) * 256;            // float4s
                const float4* src = (const float4*)(W2 + (size_t)off * 1024);
                float4* dst = (float4*)W2Lv;
                for (int i = tid; i < cnt4; i += BLOCK) dst[i] = src[i];
            }
            // Wave-parallel exclusive scan over (bucket, wave) counts.
            if (wv == 0) {
                const int cnt = nb * NWAVES;                    // 16/32/64
                int v = (lane < cnt) ? sortL[lane] : 0;
                int incl = v;
                #pragma unroll
                for (int d = 1; d < 64; d <<= 1) {
                    int t = __shfl_up(incl, d, 64);
                    if (lane >= d) incl += t;
                }
                if (lane < cnt) sortL[lane] = incl - v;
            }
            __syncthreads();

            const int slotA = sortL[locA * NWAVES + wv] + rkA;
            const int slotB = sortL[locB * NWAVES + wv] + rkB;
            permL[slotA] = ((unsigned)idA << 5) | ((unsigned)vA << 4) | (unsigned)locA;
            permL[slotB] = ((unsigned)idB << 5) | ((unsigned)vB << 4) | (unsigned)locB;
            __syncthreads();
            // Pair = consecutive slots -> same node except at bucket crossings.
            const unsigned pA = permL[wv * 128 + 2 * lane];
            const unsigned pB = permL[wv * 128 + 2 * lane + 1];
            idA = (int)(pA >> 5); vA = (int)((pA >> 4) & 1u); locA = (int)(pA & 15u);
            idB = (int)(pB >> 5); vB = (int)((pB >> 4) & 1u); locB = (int)(pB & 15u);
            __syncthreads();           // protect permL/sortL reuse next level
        }

        const int nodeA = off + locA;
        const int nodeB = off + locB;
        int bitA, bitB;

        if (__all(nodeA == nodeB)) {
            // ---------- shared path: ONE weight stream, TWO FMA chains ----------
            const int* si = subL + nodeA * NK;
            const float* xrA = x + (size_t)idA * NF;
            const float* xrB = x + (size_t)idB * NF;
            float xsA[NK], xsB[NK];
            #pragma unroll
            for (int k = 0; k < NK; ++k) {
                const int f = si[k];
                xsA[k] = xrA[f];
                xsB[k] = xrB[f];
            }

            float h1A[NH], h1B[NH];
            {
                const float4* w1g = (const float4*)(W1 + nodeA * (NH * NK));
                const float*  b1g = b1 + nodeA * NH;
                #pragma unroll
                for (int j = 0; j < NH; ++j) {
                    const float bj = b1g[j];
                    float aA = bj, aB = bj;
                    #pragma unroll
                    for (int q = 0; q < NK / 4; ++q) {
                        const float4 t = w1g[j * 4 + q];
                        aA += t.x * xsA[q * 4 + 0]; aB += t.x * xsB[q * 4 + 0];
                        aA += t.y * xsA[q * 4 + 1]; aB += t.y * xsB[q * 4 + 1];
                        aA += t.z * xsA[q * 4 + 2]; aB += t.z * xsB[q * 4 + 2];
                        aA += t.w * xsA[q * 4 + 3]; aB += t.w * xsB[q * 4 + 3];
                    }
                    h1A[j] = (aA >= 0.f) ? aA : 0.01f * aA;
                    h1B[j] = (aB >= 0.f) ? aB : 0.01f * aB;
                }
            }

            const float* w2l = W2Lv + (locA << 10);
            const float* bb2 = b2 + nodeA * NH;
            const float* w3g = W3 + nodeA * 2 * NH;
            const float bi0 = b3[nodeA * 2 + 0];
            const float bi1 = b3[nodeA * 2 + 1];
            float l0A = bi0, l1A = bi1, l0B = bi0, l1B = bi1;

            #pragma unroll 2
            for (int g = 0; g < NH; ++g) {
                const float bg = bb2[g];
                float aA = bg, aB = bg;
                const float4* row = (const float4*)(w2l + g * NH);
                #pragma unroll
                for (int q = 0; q < NH / 4; ++q) {
                    const float4 t = row[q];
                    aA += t.x * h1A[q * 4 + 0]; aB += t.x * h1B[q * 4 + 0];
                    aA += t.y * h1A[q * 4 + 1]; aB += t.y * h1B[q * 4 + 1];
                    aA += t.z * h1A[q * 4 + 2]; aB += t.z * h1B[q * 4 + 2];
                    aA += t.w * h1A[q * 4 + 3]; aB += t.w * h1B[q * 4 + 3];
                }
                const float h2A = (aA >= 0.f) ? aA : 0.01f * aA;
                const float h2B = (aB >= 0.f) ? aB : 0.01f * aB;
                const float wa = w3g[g];
                const float wb = w3g[NH + g];
                l0A += wa * h2A; l1A += wb * h2A;
                l0B += wa * h2B; l1B += wb * h2B;
            }
            bitA = (l0A < l1A) ? 1 : 0;
            bitB = (l0B < l1B) ? 1 : 0;
        } else {
            // ---------- dual path: r5 body per sample (boundary waves) ----------
            #pragma unroll 1
            for (int s2 = 0; s2 < 2; ++s2) {
                const int idS  = s2 ? idB : idA;
                const int locS = s2 ? locB : locA;
                const int node = off + locS;
                const int* si = subL + node * NK;
                const float* xr = x + (size_t)idS * NF;
                float xs[NK];
                #pragma unroll
                for (int k = 0; k < NK; ++k) xs[k] = xr[si[k]];

                float h1v[NH];
                const float4* w1g = (const float4*)(W1 + node * (NH * NK));
                const float*  b1g = b1 + node * NH;
                #pragma unroll
                for (int j = 0; j < NH; ++j) {
                    float acc = b1g[j];
                    #pragma unroll
                    for (int q = 0; q < NK / 4; ++q) {
                        const float4 t = w1g[j * 4 + q];
                        acc += t.x * xs[q * 4 + 0];
                        acc += t.y * xs[q * 4 + 1];
                        acc += t.z * xs[q * 4 + 2];
                        acc += t.w * xs[q * 4 + 3];
                    }
                    h1v[j] = (acc >= 0.f) ? acc : 0.01f * acc;
                }

                const float* w2l = W2Lv + (locS << 10);
                const float* bb2 = b2 + node * NH;
                const float* w3g = W3 + node * 2 * NH;
                float l0 = b3[node * 2 + 0];
                float l1 = b3[node * 2 + 1];
                #pragma unroll 2
                for (int g = 0; g < NH; ++g) {
                    float acc = bb2[g];
                    const float4* row = (const float4*)(w2l + g * NH);
                    #pragma unroll
                    for (int q = 0; q < NH / 4; ++q) {
                        const float4 t = row[q];
                        acc += t.x * h1v[q * 4 + 0];
                        acc += t.y * h1v[q * 4 + 1];
                        acc += t.z * h1v[q * 4 + 2];
                        acc += t.w * h1v[q * 4 + 3];
                    }
                    const float h2 = (acc >= 0.f) ? acc : 0.01f * acc;
                    l0 += w3g[g]      * h2;
                    l1 += w3g[NH + g] * h2;
                }
                const int bit = (l0 < l1) ? 1 : 0;
                if (s2) bitB = bit; else bitA = bit;
            }
        }

        locA = 2 * locA + bitA;
        locB = 2 * locB + bitB;
        off = 2 * off + 1;   // node offsets: 0, 1, 3, 7
    }

    if (vA) out[idA] = leaf_best[locA];
    if (vB) out[idB] = leaf_best[locB];
}

extern "C" void kernel_launch(void* const* d_in, const int* in_sizes, int n_in,
                              void* d_out, int out_size, void* d_ws, size_t ws_size,
                              hipStream_t stream) {
    const float* x         = (const float*)d_in[0];
    const float* W1        = (const float*)d_in[1];
    const float* b1        = (const float*)d_in[2];
    const float* W2        = (const float*)d_in[3];
    const float* b2        = (const float*)d_in[4];
    const float* W3        = (const float*)d_in[5];
    const float* b3        = (const float*)d_in[6];
    const float* leaf_best = (const float*)d_in[7];
    const int*   subset    = (const int*)d_in[8];

    const int N = in_sizes[0] / NF;
    const int grid = (N + SPB - 1) / SPB;
    tree_mlp_kernel<<<grid, BLOCK, 0, stream>>>(
        x, W1, b1, W2, b2, W3, b3, leaf_best, subset, (float*)d_out, N);
}